// Round 3
// baseline (337.886 us; speedup 1.0000x reference)
//
#include <hip/hip_runtime.h>
#include <hip/hip_bf16.h>
#include <stdint.h>

// ---------------------------------------------------------------------------
// Attention_47330539602252 on MI355X (gfx950). fp32 I/O, bf16 MFMA compute.
// B=8 N=1024 C=768 H=12 hd=64; quad2: t=(s*0.125+5)^2, row-normalized.
// R3: (a) pre-convert inputs to bf16; (b) GEMMs use global_load_lds width-16
//     (m97 structure); (c) attn is BARRIER-FREE: Q/K/V frags straight from
//     global (L2-resident, V stored pre-transposed [b,h,d,n]); P round-trip
//     through wave-private LDS (same-wave DS is in-order); rowsum via
//     ones-fragment MFMA (consistent with bf16 P used in PV numerator).
// MFMA layouts (HW-verified):
//   A-frag: A[m=lane&15][k=quad*8+j]   B-frag: B[n=lane&15][k=quad*8+j]
//   C/D:    col=lane&15, row=quad*4+reg
// ---------------------------------------------------------------------------

typedef short  s8v  __attribute__((ext_vector_type(8)));  // 8 bf16 raw bits
typedef float  f4v  __attribute__((ext_vector_type(4)));

__device__ inline uint16_t f2bf(float f) {
    union { float f; uint32_t u; } c; c.f = f;
    uint32_t u = c.u;
    u += 0x7fffu + ((u >> 16) & 1u);   // RNE
    return (uint16_t)(u >> 16);
}

// async global->LDS, 16B per lane (LDS dest must be contiguous in lane order)
__device__ inline void cp16(const uint16_t* g, uint16_t* l) {
    __builtin_amdgcn_global_load_lds(
        (const __attribute__((address_space(1))) void*)g,
        (__attribute__((address_space(3))) void*)l, 16, 0, 0);
}

// ---------------------------------------------------------------------------
// fp32 -> bf16 elementwise, 8 elems/thread (16B in / 16B out... 32B in)
// ---------------------------------------------------------------------------
__global__ __launch_bounds__(256) void cvt_bf16(
    const float* __restrict__ s, uint16_t* __restrict__ d, int n8)
{
    int i = blockIdx.x * 256 + threadIdx.x;
    if (i >= n8) return;
    const float4* sp = reinterpret_cast<const float4*>(s + (size_t)i * 8);
    float4 a = sp[0], b = sp[1];
    s8v o;
    o[0] = (short)f2bf(a.x); o[1] = (short)f2bf(a.y);
    o[2] = (short)f2bf(a.z); o[3] = (short)f2bf(a.w);
    o[4] = (short)f2bf(b.x); o[5] = (short)f2bf(b.y);
    o[6] = (short)f2bf(b.z); o[7] = (short)f2bf(b.w);
    *reinterpret_cast<s8v*>(d + (size_t)i * 8) = o;
}

// ---------------------------------------------------------------------------
// GEMM-BT: C[M,N] = A[M,K] @ Bm[N,K]^T, bf16 in, K%32==0. 128x128 tile,
// 4 waves (2x2), 4x4 mfma tiles/wave, global_load_lds staging (unpadded LDS;
// b128 frag reads distribute evenly across banks -> structural 8cyc, no
// conflict). EPI==0: scatter q/k (n-major) + v TRANSPOSED [b,h,d,n].
// EPI==1: +bias, fp32 Cout[M,768].
// ---------------------------------------------------------------------------
template <int EPI>
__global__ __launch_bounds__(256) void gemm_bt(
    const uint16_t* __restrict__ A, const uint16_t* __restrict__ Bm,
    uint16_t* __restrict__ qb, uint16_t* __restrict__ kb, uint16_t* __restrict__ vb,
    const float* __restrict__ bias, float* __restrict__ Cout, int K)
{
    __shared__ uint16_t Al[128 * 32];
    __shared__ uint16_t Bl[128 * 32];

    const int tid  = threadIdx.x;
    const int wave = tid >> 6, lane = tid & 63;
    const int quad = lane >> 4, l16 = lane & 15;
    const int wM = wave >> 1, wN = wave & 1;
    const int bM = blockIdx.x, bN = blockIdx.y;

    f4v acc[4][4];
#pragma unroll
    for (int i = 0; i < 4; i++)
#pragma unroll
        for (int j = 0; j < 4; j++) { f4v z = {0.f, 0.f, 0.f, 0.f}; acc[i][j] = z; }

    const uint16_t* Ag = A  + (size_t)bM * 128 * K;
    const uint16_t* Bg = Bm + (size_t)bN * 128 * K;

    // per-thread staging slots (16B each): e = tid*8 elems, +2048 for 2nd
    const int e0 = tid * 8;
    const int r0 = e0 >> 5, c0 = e0 & 31;

    for (int kc = 0; kc < K; kc += 32) {
        __syncthreads();
        cp16(Ag + (size_t)r0 * K + kc + c0,        &Al[e0]);
        cp16(Ag + (size_t)(r0 + 64) * K + kc + c0, &Al[e0 + 2048]);
        cp16(Bg + (size_t)r0 * K + kc + c0,        &Bl[e0]);
        cp16(Bg + (size_t)(r0 + 64) * K + kc + c0, &Bl[e0 + 2048]);
        __syncthreads();   // compiler emits s_waitcnt vmcnt(0) before barrier

        s8v af[4], bf[4];
#pragma unroll
        for (int t = 0; t < 4; t++) {
            af[t] = *reinterpret_cast<const s8v*>(&Al[(wM * 64 + t * 16 + l16) * 32 + quad * 8]);
            bf[t] = *reinterpret_cast<const s8v*>(&Bl[(wN * 64 + t * 16 + l16) * 32 + quad * 8]);
        }
#pragma unroll
        for (int tm = 0; tm < 4; tm++)
#pragma unroll
            for (int tn = 0; tn < 4; tn++)
                acc[tm][tn] = __builtin_amdgcn_mfma_f32_16x16x32_bf16(af[tm], bf[tn], acc[tm][tn], 0, 0, 0);
    }

#pragma unroll
    for (int tm = 0; tm < 4; tm++) {
#pragma unroll
        for (int tn = 0; tn < 4; tn++) {
            const int col = bN * 128 + wN * 64 + tn * 16 + l16;
#pragma unroll
            for (int reg = 0; reg < 4; reg++) {
                const int row = bM * 128 + wM * 64 + tm * 16 + quad * 4 + reg;
                float val = acc[tm][tn][reg];
                if (EPI == 0) {
                    const int three = col / 768;
                    const int rem   = col - three * 768;
                    const int h = rem >> 6, d = rem & 63;
                    const int b = row >> 10, n = row & 1023;
                    if (three == 0)
                        qb[((size_t)((b * 12 + h) * 1024 + n)) * 64 + d] = f2bf(val);
                    else if (three == 1)
                        kb[((size_t)((b * 12 + h) * 1024 + n)) * 64 + d] = f2bf(val);
                    else  // V stored transposed: [b,h,d,n]
                        vb[((size_t)((b * 12 + h) * 64 + d)) * 1024 + n] = f2bf(val);
                } else {
                    Cout[(size_t)row * 768 + col] = val + bias[col];
                }
            }
        }
    }
}

// ---------------------------------------------------------------------------
// Barrier-free fused quad2 attention. Grid: x=16 Q-tiles (64 rows), y=96 bh.
// Wave w owns Q rows [qt*64+w*16, +16); m-loop over 16 x 64-col tiles.
// All Q/K/V fragments are direct global loads (coalesced dwordx4, L2-hot);
// P goes C-layout -> wave-private LDS -> A-layout; rowsum via ones-MFMA.
// ---------------------------------------------------------------------------
__global__ __launch_bounds__(256) void attn_quad(
    const uint16_t* __restrict__ Q, const uint16_t* __restrict__ K,
    const uint16_t* __restrict__ VT, uint16_t* __restrict__ O)
{
    const int qt = blockIdx.x;      // 0..15
    const int bh = blockIdx.y;      // 0..95
    const uint16_t* Qp = Q  + (size_t)bh * 65536;
    const uint16_t* Kp = K  + (size_t)bh * 65536;
    const uint16_t* Vp = VT + (size_t)bh * 65536;   // [d=64][n=1024]

    const int tid  = threadIdx.x;
    const int wave = tid >> 6, lane = tid & 63;
    const int quad = lane >> 4, l16 = lane & 15;

    __shared__ uint16_t Pl[4][16][72];   // wave-private P tile [qrow][m]

    // Q fragments: rows wave*16+l16, k-dim = d (64 -> two frags)
    const uint16_t* qptr = Qp + (size_t)(qt * 64 + wave * 16 + l16) * 64 + quad * 8;
    const s8v qf0 = *reinterpret_cast<const s8v*>(qptr);
    const s8v qf1 = *reinterpret_cast<const s8v*>(qptr + 32);

    s8v ones;
#pragma unroll
    for (int i = 0; i < 8; i++) ones[i] = (short)0x3F80;   // bf16 1.0

    f4v U[4], U5;
#pragma unroll
    for (int i = 0; i < 4; i++) { f4v z = {0.f, 0.f, 0.f, 0.f}; U[i] = z; }
    { f4v z = {0.f, 0.f, 0.f, 0.f}; U5 = z; }

    for (int mt = 0; mt < 16; mt++) {
        const uint16_t* Kt = Kp + (size_t)mt * 64 * 64;

        // S = Q @ K^T : 16 q-rows x 64 m-cols; K frags direct from global
        f4v sacc[4];
#pragma unroll
        for (int ct = 0; ct < 4; ct++) {
            const uint16_t* kp = Kt + (size_t)(ct * 16 + l16) * 64 + quad * 8;
            s8v k0 = *reinterpret_cast<const s8v*>(kp);
            s8v k1 = *reinterpret_cast<const s8v*>(kp + 32);
            f4v z = {0.f, 0.f, 0.f, 0.f};
            z = __builtin_amdgcn_mfma_f32_16x16x32_bf16(qf0, k0, z, 0, 0, 0);
            z = __builtin_amdgcn_mfma_f32_16x16x32_bf16(qf1, k1, z, 0, 0, 0);
            sacc[ct] = z;
        }

        // t = (s*0.125+5)^2 -> bf16 -> wave-private LDS (C-layout -> A-layout)
#pragma unroll
        for (int ct = 0; ct < 4; ct++) {
#pragma unroll
            for (int rp = 0; rp < 4; rp += 2) {
                float a = sacc[ct][rp]     * 0.125f + 5.0f;
                float b = sacc[ct][rp + 1] * 0.125f + 5.0f;
                __hip_bfloat162 pk = __float22bfloat162_rn(float2{a * a, b * b});
                union { __hip_bfloat162 v; uint32_t u; } cc; cc.v = pk;
                Pl[wave][quad * 4 + rp][ct * 16 + l16]     = (uint16_t)(cc.u & 0xffffu);
                Pl[wave][quad * 4 + rp + 1][ct * 16 + l16] = (uint16_t)(cc.u >> 16);
            }
        }

        // U += P @ V ; rowsum via ones-fragment MFMA (same-wave DS in-order)
#pragma unroll
        for (int kc = 0; kc < 2; kc++) {
            s8v pf = *reinterpret_cast<const s8v*>(&Pl[wave][l16][kc * 32 + quad * 8]);
            U5 = __builtin_amdgcn_mfma_f32_16x16x32_bf16(pf, ones, U5, 0, 0, 0);
#pragma unroll
            for (int ct = 0; ct < 4; ct++) {
                const uint16_t* vp = Vp + (size_t)(ct * 16 + l16) * 1024
                                        + mt * 64 + kc * 32 + quad * 8;
                s8v vf = *reinterpret_cast<const s8v*>(vp);
                U[ct] = __builtin_amdgcn_mfma_f32_16x16x32_bf16(pf, vf, U[ct], 0, 0, 0);
            }
        }
    }

    // epilogue: O[b, n, h*64+d] = U / rowsum (bf16 intermediate for proj GEMM)
    const int b = bh / 12, h = bh - (bh / 12) * 12;
    float inv[4];
#pragma unroll
    for (int reg = 0; reg < 4; reg++) inv[reg] = 1.0f / U5[reg];
#pragma unroll
    for (int ct = 0; ct < 4; ct++) {
#pragma unroll
        for (int reg = 0; reg < 4; reg++) {
            const int n = qt * 64 + wave * 16 + quad * 4 + reg;
            const int d = ct * 16 + l16;
            O[((size_t)(b * 1024 + n)) * 768 + h * 64 + d] = f2bf(U[ct][reg] * inv[reg]);
        }
    }
}

// ---------------------------------------------------------------------------
extern "C" void kernel_launch(void* const* d_in, const int* in_sizes, int n_in,
                              void* d_out, int out_size, void* d_ws, size_t ws_size,
                              hipStream_t stream)
{
    const float* x      = (const float*)d_in[0];   // [8,1024,768]
    const float* qkv_w  = (const float*)d_in[1];   // [2304,768]
    const float* proj_w = (const float*)d_in[2];   // [768,768]
    const float* proj_b = (const float*)d_in[3];   // [768]
    float* out = (float*)d_out;                    // [8,1024,768] fp32

    const size_t NEL = (size_t)8 * 1024 * 768;     // 6291456
    uint16_t* xb  = (uint16_t*)d_ws;               // bf16 x
    uint16_t* qwb = xb  + NEL;                     // bf16 qkv_w (1769472)
    uint16_t* pwb = qwb + 1769472;                 // bf16 proj_w (589824)
    uint16_t* qb  = pwb + 589824;                  // bf16 [B,H,N,64]
    uint16_t* kb  = qb  + NEL;                     // bf16 [B,H,N,64]
    uint16_t* vb  = kb  + NEL;                     // bf16 [B,H,64,N] (transposed)
    uint16_t* ao  = vb  + NEL;                     // bf16 attn out [8192,768]

    cvt_bf16<<<3072, 256, 0, stream>>>(x,      xb,  786432);
    cvt_bf16<<<864,  256, 0, stream>>>(qkv_w,  qwb, 221184);
    cvt_bf16<<<288,  256, 0, stream>>>(proj_w, pwb, 73728);

    // QKV: [8192,768] @ [2304,768]^T -> scatter bf16 q/k/v (v transposed)
    gemm_bt<0><<<dim3(64, 18), 256, 0, stream>>>(xb, qwb, qb, kb, vb, nullptr, nullptr, 768);
    // fused quad2 attention -> ao [8192,768] bf16
    attn_quad<<<dim3(16, 96), 256, 0, stream>>>(qb, kb, vb, ao);
    // proj: [8192,768] @ [768,768]^T + bias -> fp32 out
    gemm_bt<1><<<dim3(64, 6), 256, 0, stream>>>(ao, pwb, nullptr, nullptr, nullptr, proj_b, out, 768);
}

// Round 4
// 211.316 us; speedup vs baseline: 1.5990x; 1.5990x over previous
//
#include <hip/hip_runtime.h>
#include <hip/hip_bf16.h>
#include <stdint.h>

// ---------------------------------------------------------------------------
// Attention_47330539602252 on MI355X (gfx950). fp32 I/O, bf16 MFMA compute.
// B=8 N=1024 C=768 H=12 hd=64; quad2: t=(s*0.125+5)^2, row-normalized.
// R4: attn back to LDS-staged K/V (R3's direct-global was latency-bound) with
//  - 64 q-rows/wave (4 subtiles): K/V frags hoisted, reused 4x -> 72 MFMA
//    per 24 LDS reads per wave-iter (R2 was 1:1)
//  - S^T = K@Q^T so P packs into ds_write_b64 (4 writes vs 16 scalar)
//  - V pre-transposed [b,h,d,n] in global -> cp16 staging, no transpose
//  - rowsum via ones-MFMA (exactly consistent with bf16 P fed to PV)
// MFMA layouts (HW-verified):
//   A-frag: A[m=lane&15][k=quad*8+j]   B-frag: B[n=lane&15][k=quad*8+j]
//   C/D:    col(n)=lane&15, row(m)=quad*4+reg
// ---------------------------------------------------------------------------

typedef short  s8v  __attribute__((ext_vector_type(8)));  // 8 bf16 raw bits
typedef float  f4v  __attribute__((ext_vector_type(4)));

__device__ inline uint16_t f2bf(float f) {
    union { float f; uint32_t u; } c; c.f = f;
    uint32_t u = c.u;
    u += 0x7fffu + ((u >> 16) & 1u);   // RNE
    return (uint16_t)(u >> 16);
}
__device__ inline uint32_t pack2bf(float a, float b) {
    union { __hip_bfloat162 v; uint32_t u; } c;
    c.v = __float22bfloat162_rn(float2{a, b});   // x=a -> low 16 bits
    return c.u;
}

// async global->LDS, 16B per lane (LDS dest contiguous in lane order)
__device__ inline void cp16(const uint16_t* g, uint16_t* l) {
    __builtin_amdgcn_global_load_lds(
        (const __attribute__((address_space(1))) void*)g,
        (__attribute__((address_space(3))) void*)l, 16, 0, 0);
}

// ---------------------------------------------------------------------------
// fp32 -> bf16 for all three inputs in one launch (dests contiguous in ws).
// ---------------------------------------------------------------------------
__global__ __launch_bounds__(256) void cvt_all(
    const float* __restrict__ x, const float* __restrict__ qw,
    const float* __restrict__ pw, uint16_t* __restrict__ dst)
{
    // totals in 8-elem groups: x 786432 | qkv_w 221184 | proj_w 73728
    int i = blockIdx.x * 256 + threadIdx.x;
    if (i >= 1081344) return;
    const float* s;
    if (i < 786432)       s = x  + (size_t)i * 8;
    else if (i < 1007616) s = qw + ((size_t)i - 786432) * 8;
    else                  s = pw + ((size_t)i - 1007616) * 8;
    const float4* sp = reinterpret_cast<const float4*>(s);
    float4 a = sp[0], b = sp[1];
    s8v o;
    o[0] = (short)f2bf(a.x); o[1] = (short)f2bf(a.y);
    o[2] = (short)f2bf(a.z); o[3] = (short)f2bf(a.w);
    o[4] = (short)f2bf(b.x); o[5] = (short)f2bf(b.y);
    o[6] = (short)f2bf(b.z); o[7] = (short)f2bf(b.w);
    *reinterpret_cast<s8v*>(dst + (size_t)i * 8) = o;
}

// ---------------------------------------------------------------------------
// GEMM-BT: C[M,N] = A[M,K] @ Bm[N,K]^T, bf16 in, K%32==0. 128x128 tile,
// 4 waves (2x2), 4x4 mfma tiles/wave, global_load_lds width-16 staging.
// EPI==0: scatter q/k (n-major) + v TRANSPOSED [b,h,d,n]. EPI==1: +bias fp32.
// ---------------------------------------------------------------------------
template <int EPI>
__global__ __launch_bounds__(256) void gemm_bt(
    const uint16_t* __restrict__ A, const uint16_t* __restrict__ Bm,
    uint16_t* __restrict__ qb, uint16_t* __restrict__ kb, uint16_t* __restrict__ vb,
    const float* __restrict__ bias, float* __restrict__ Cout, int K)
{
    __shared__ uint16_t Al[128 * 32];
    __shared__ uint16_t Bl[128 * 32];

    const int tid  = threadIdx.x;
    const int wave = tid >> 6, lane = tid & 63;
    const int quad = lane >> 4, l16 = lane & 15;
    const int wM = wave >> 1, wN = wave & 1;
    const int bM = blockIdx.x, bN = blockIdx.y;

    f4v acc[4][4];
#pragma unroll
    for (int i = 0; i < 4; i++)
#pragma unroll
        for (int j = 0; j < 4; j++) { f4v z = {0.f, 0.f, 0.f, 0.f}; acc[i][j] = z; }

    const uint16_t* Ag = A  + (size_t)bM * 128 * K;
    const uint16_t* Bg = Bm + (size_t)bN * 128 * K;

    const int e0 = tid * 8;
    const int r0 = e0 >> 5, c0 = e0 & 31;

    for (int kc = 0; kc < K; kc += 32) {
        __syncthreads();
        cp16(Ag + (size_t)r0 * K + kc + c0,        &Al[e0]);
        cp16(Ag + (size_t)(r0 + 64) * K + kc + c0, &Al[e0 + 2048]);
        cp16(Bg + (size_t)r0 * K + kc + c0,        &Bl[e0]);
        cp16(Bg + (size_t)(r0 + 64) * K + kc + c0, &Bl[e0 + 2048]);
        __syncthreads();

        s8v af[4], bf[4];
#pragma unroll
        for (int t = 0; t < 4; t++) {
            af[t] = *reinterpret_cast<const s8v*>(&Al[(wM * 64 + t * 16 + l16) * 32 + quad * 8]);
            bf[t] = *reinterpret_cast<const s8v*>(&Bl[(wN * 64 + t * 16 + l16) * 32 + quad * 8]);
        }
#pragma unroll
        for (int tm = 0; tm < 4; tm++)
#pragma unroll
            for (int tn = 0; tn < 4; tn++)
                acc[tm][tn] = __builtin_amdgcn_mfma_f32_16x16x32_bf16(af[tm], bf[tn], acc[tm][tn], 0, 0, 0);
    }

#pragma unroll
    for (int tm = 0; tm < 4; tm++) {
#pragma unroll
        for (int tn = 0; tn < 4; tn++) {
            const int col = bN * 128 + wN * 64 + tn * 16 + l16;
#pragma unroll
            for (int reg = 0; reg < 4; reg++) {
                const int row = bM * 128 + wM * 64 + tm * 16 + quad * 4 + reg;
                float val = acc[tm][tn][reg];
                if (EPI == 0) {
                    const int three = col / 768;
                    const int rem   = col - three * 768;
                    const int h = rem >> 6, d = rem & 63;
                    const int b = row >> 10, n = row & 1023;
                    if (three == 0)
                        qb[((size_t)((b * 12 + h) * 1024 + n)) * 64 + d] = f2bf(val);
                    else if (three == 1)
                        kb[((size_t)((b * 12 + h) * 1024 + n)) * 64 + d] = f2bf(val);
                    else  // V transposed: [b,h,d,n]
                        vb[((size_t)((b * 12 + h) * 64 + d)) * 1024 + n] = f2bf(val);
                } else {
                    Cout[(size_t)row * 768 + col] = val + bias[col];
                }
            }
        }
    }
}

// ---------------------------------------------------------------------------
// Fused quad2 attention. Grid: x=8 (128 q-rows/block), y=96 (b*12+h).
// Block = 128 threads = 2 waves; wave owns 64 q-rows as 4 subtiles of 16.
// Per m-tile (64 keys): cp16-stage K[m][d], V^T[d][m]; hoist K/V frags to
// regs; per subtile: S^T = K@Q^T -> t=(s/8+5)^2 -> packed b64 P writes ->
// PV + ones-MFMA rowsum. Final O = U/rowsum.
// ---------------------------------------------------------------------------
__global__ __launch_bounds__(128, 2) void attn_quad(
    const uint16_t* __restrict__ Q, const uint16_t* __restrict__ K,
    const uint16_t* __restrict__ VT, uint16_t* __restrict__ O)
{
    const int qt = blockIdx.x;      // 0..7
    const int bh = blockIdx.y;      // 0..95
    const uint16_t* Qp = Q  + (size_t)bh * 65536;
    const uint16_t* Kp = K  + (size_t)bh * 65536;
    const uint16_t* Vp = VT + (size_t)bh * 65536;   // [d=64][n=1024]

    const int tid  = threadIdx.x;
    const int wave = tid >> 6, lane = tid & 63;
    const int quad = lane >> 4, l16 = lane & 15;

    __shared__ uint16_t Kl[64 * 64];     // [m][d]
    __shared__ uint16_t Vl[64 * 64];     // [d][m]
    __shared__ uint16_t Pl[2][16][80];   // per-wave [qrow][m], stride 80 (16B-aligned rows)

    // Q fragments (one-time, direct global): rows qt*128 + wave*64 + s*16 + l16
    s8v qf[4][2];
#pragma unroll
    for (int s = 0; s < 4; s++) {
        const uint16_t* qp = Qp + (size_t)(qt * 128 + wave * 64 + s * 16 + l16) * 64 + quad * 8;
        qf[s][0] = *reinterpret_cast<const s8v*>(qp);
        qf[s][1] = *reinterpret_cast<const s8v*>(qp + 32);
    }

    s8v ones;
#pragma unroll
    for (int i = 0; i < 8; i++) ones[i] = (short)0x3F80;   // bf16 1.0

    f4v U[4][4], U5[4];
#pragma unroll
    for (int s = 0; s < 4; s++) {
        f4v z = {0.f, 0.f, 0.f, 0.f};
        U5[s] = z;
#pragma unroll
        for (int c = 0; c < 4; c++) U[s][c] = z;
    }

    for (int mt = 0; mt < 16; mt++) {
        __syncthreads();
        // K tile: contiguous 8KB in global ([m][d] row-major, m=mt*64..)
#pragma unroll
        for (int r = 0; r < 4; r++) {
            const int e = (tid + r * 128) * 8;
            cp16(Kp + (size_t)mt * 4096 + e, &Kl[e]);
        }
        // V tile: rows d of VT, cols mt*64..+64
#pragma unroll
        for (int r = 0; r < 4; r++) {
            const int e = (tid + r * 128) * 8;
            const int d = e >> 6, m = e & 63;
            cp16(Vp + (size_t)d * 1024 + mt * 64 + m, &Vl[e]);
        }
        __syncthreads();   // vmcnt(0) drain before barrier

        // hoist K/V fragments (reused by all 4 subtiles)
        s8v kf[4][2], vf[4][2];
#pragma unroll
        for (int c = 0; c < 4; c++) {
            const uint16_t* kp = &Kl[(c * 16 + l16) * 64 + quad * 8];
            kf[c][0] = *reinterpret_cast<const s8v*>(kp);
            kf[c][1] = *reinterpret_cast<const s8v*>(kp + 32);
            const uint16_t* vp = &Vl[(c * 16 + l16) * 64 + quad * 8];
            vf[c][0] = *reinterpret_cast<const s8v*>(vp);
            vf[c][1] = *reinterpret_cast<const s8v*>(vp + 32);
        }

#pragma unroll
        for (int s = 0; s < 4; s++) {
            // S^T = K @ Q^T : C col=l16=qrow, row=quad*4+reg = m (within cm tile)
            f4v st[4];
#pragma unroll
            for (int cm = 0; cm < 4; cm++) {
                f4v z = {0.f, 0.f, 0.f, 0.f};
                z = __builtin_amdgcn_mfma_f32_16x16x32_bf16(kf[cm][0], qf[s][0], z, 0, 0, 0);
                z = __builtin_amdgcn_mfma_f32_16x16x32_bf16(kf[cm][1], qf[s][1], z, 0, 0, 0);
                st[cm] = z;
            }
            // t = (s*0.125+5)^2 -> packed b64 write: Pl[qrow=l16][m=cm*16+quad*4 ..+3]
#pragma unroll
            for (int cm = 0; cm < 4; cm++) {
                float t0 = st[cm][0] * 0.125f + 5.0f; t0 *= t0;
                float t1 = st[cm][1] * 0.125f + 5.0f; t1 *= t1;
                float t2 = st[cm][2] * 0.125f + 5.0f; t2 *= t2;
                float t3 = st[cm][3] * 0.125f + 5.0f; t3 *= t3;
                uint2 pk; pk.x = pack2bf(t0, t1); pk.y = pack2bf(t2, t3);
                *reinterpret_cast<uint2*>(&Pl[wave][l16][cm * 16 + quad * 4]) = pk;
            }
            // U += P @ V ; rowsum via ones-MFMA (same-wave DS in-order)
#pragma unroll
            for (int kc = 0; kc < 2; kc++) {
                s8v pf = *reinterpret_cast<const s8v*>(&Pl[wave][l16][kc * 32 + quad * 8]);
                U5[s] = __builtin_amdgcn_mfma_f32_16x16x32_bf16(pf, ones, U5[s], 0, 0, 0);
#pragma unroll
                for (int cd = 0; cd < 4; cd++)
                    U[s][cd] = __builtin_amdgcn_mfma_f32_16x16x32_bf16(pf, vf[cd][kc], U[s][cd], 0, 0, 0);
            }
        }
    }

    // epilogue: O[b, n, h*64+d] = U / rowsum (bf16 intermediate for proj GEMM)
    const int b = bh / 12, h = bh - (bh / 12) * 12;
#pragma unroll
    for (int s = 0; s < 4; s++) {
        float inv[4];
#pragma unroll
        for (int reg = 0; reg < 4; reg++) inv[reg] = 1.0f / U5[s][reg];
#pragma unroll
        for (int cd = 0; cd < 4; cd++) {
#pragma unroll
            for (int reg = 0; reg < 4; reg++) {
                const int n = qt * 128 + wave * 64 + s * 16 + quad * 4 + reg;
                const int d = cd * 16 + l16;
                O[((size_t)(b * 1024 + n)) * 768 + h * 64 + d] = f2bf(U[s][cd][reg] * inv[reg]);
            }
        }
    }
}

// ---------------------------------------------------------------------------
extern "C" void kernel_launch(void* const* d_in, const int* in_sizes, int n_in,
                              void* d_out, int out_size, void* d_ws, size_t ws_size,
                              hipStream_t stream)
{
    const float* x      = (const float*)d_in[0];   // [8,1024,768]
    const float* qkv_w  = (const float*)d_in[1];   // [2304,768]
    const float* proj_w = (const float*)d_in[2];   // [768,768]
    const float* proj_b = (const float*)d_in[3];   // [768]
    float* out = (float*)d_out;                    // [8,1024,768] fp32

    const size_t NEL = (size_t)8 * 1024 * 768;     // 6291456
    uint16_t* xb  = (uint16_t*)d_ws;               // bf16 x
    uint16_t* qwb = xb  + NEL;                     // bf16 qkv_w (1769472)
    uint16_t* pwb = qwb + 1769472;                 // bf16 proj_w (589824)
    uint16_t* qb  = pwb + 589824;                  // bf16 [B,H,N,64]
    uint16_t* kb  = qb  + NEL;                     // bf16 [B,H,N,64]
    uint16_t* vb  = kb  + NEL;                     // bf16 [B,H,64,N] (transposed)
    uint16_t* ao  = vb  + NEL;                     // bf16 attn out [8192,768]

    cvt_all<<<4224, 256, 0, stream>>>(x, qkv_w, proj_w, xb);

    // QKV: [8192,768] @ [2304,768]^T -> scatter bf16 q/k/v (v transposed)
    gemm_bt<0><<<dim3(64, 18), 256, 0, stream>>>(xb, qwb, qb, kb, vb, nullptr, nullptr, 768);
    // fused quad2 attention -> ao [8192,768] bf16
    attn_quad<<<dim3(8, 96), 128, 0, stream>>>(qb, kb, vb, ao);
    // proj: [8192,768] @ [768,768]^T + bias -> fp32 out
    gemm_bt<1><<<dim3(64, 6), 256, 0, stream>>>(ao, pwb, nullptr, nullptr, nullptr, proj_b, out, 768);
}

// Round 8
// 208.695 us; speedup vs baseline: 1.6190x; 1.0126x over previous
//
#include <hip/hip_runtime.h>
#include <hip/hip_bf16.h>
#include <stdint.h>

// ---------------------------------------------------------------------------
// Attention_47330539602252 on MI355X (gfx950). fp32 I/O, bf16 MFMA compute.
// B=8 N=1024 C=768 H=12 hd=64; quad2: t=(s*0.125+5)^2, row-normalized.
// R8 = EXACT R4 (last PASS, 211us) + ONE change: attn-internal XOR chunk
// swizzle on Kl/Vl (cp16 stages logical chunk c^(row&7) at physical chunk c;
// reads XOR back). Kills the 16-way bank serialization on every b128
// fragment read (R4 rows were 128B = bank-aligned). No inter-kernel
// interface changed. The V-split GEMM (R5-R7, 3x fail at ~0.12) is parked.
// MFMA layouts (HW-verified):
//   A-frag: A[m=lane&15][k=quad*8+j]   B-frag: B[n=lane&15][k=quad*8+j]
//   C/D:    col(n)=lane&15, row(m)=quad*4+reg
// ---------------------------------------------------------------------------

typedef short  s8v  __attribute__((ext_vector_type(8)));  // 8 bf16 raw bits
typedef float  f4v  __attribute__((ext_vector_type(4)));

__device__ inline uint16_t f2bf(float f) {
    union { float f; uint32_t u; } c; c.f = f;
    uint32_t u = c.u;
    u += 0x7fffu + ((u >> 16) & 1u);   // RNE
    return (uint16_t)(u >> 16);
}
__device__ inline uint32_t pack2bf(float a, float b) {
    union { __hip_bfloat162 v; uint32_t u; } c;
    c.v = __float22bfloat162_rn(float2{a, b});   // x=a -> low 16 bits
    return c.u;
}

// async global->LDS, 16B per lane (LDS dest = wave-uniform base + lane*16)
__device__ inline void cp16(const uint16_t* g, uint16_t* l) {
    __builtin_amdgcn_global_load_lds(
        (const __attribute__((address_space(1))) void*)g,
        (__attribute__((address_space(3))) void*)l, 16, 0, 0);
}

// ---------------------------------------------------------------------------
// fp32 -> bf16 for all three inputs in one launch (dests contiguous in ws).
// ---------------------------------------------------------------------------
__global__ __launch_bounds__(256) void cvt_all(
    const float* __restrict__ x, const float* __restrict__ qw,
    const float* __restrict__ pw, uint16_t* __restrict__ dst)
{
    // totals in 8-elem groups: x 786432 | qkv_w 221184 | proj_w 73728
    int i = blockIdx.x * 256 + threadIdx.x;
    if (i >= 1081344) return;
    const float* s;
    if (i < 786432)       s = x  + (size_t)i * 8;
    else if (i < 1007616) s = qw + ((size_t)i - 786432) * 8;
    else                  s = pw + ((size_t)i - 1007616) * 8;
    const float4* sp = reinterpret_cast<const float4*>(s);
    float4 a = sp[0], b = sp[1];
    s8v o;
    o[0] = (short)f2bf(a.x); o[1] = (short)f2bf(a.y);
    o[2] = (short)f2bf(a.z); o[3] = (short)f2bf(a.w);
    o[4] = (short)f2bf(b.x); o[5] = (short)f2bf(b.y);
    o[6] = (short)f2bf(b.z); o[7] = (short)f2bf(b.w);
    *reinterpret_cast<s8v*>(dst + (size_t)i * 8) = o;
}

// ---------------------------------------------------------------------------
// GEMM-BT (byte-exact R4): C[M,N] = A[M,K] @ Bm[N,K]^T, bf16 in, K%32==0.
// 128x128 tile, 4 waves (2x2), 4x4 mfma tiles/wave, BK=32 cp16 staging.
// EPI==0: scatter q/k (n-major) + v TRANSPOSED [b,h,d,n]. EPI==1: +bias fp32.
// ---------------------------------------------------------------------------
template <int EPI>
__global__ __launch_bounds__(256) void gemm_bt(
    const uint16_t* __restrict__ A, const uint16_t* __restrict__ Bm,
    uint16_t* __restrict__ qb, uint16_t* __restrict__ kb, uint16_t* __restrict__ vb,
    const float* __restrict__ bias, float* __restrict__ Cout, int K)
{
    __shared__ uint16_t Al[128 * 32];
    __shared__ uint16_t Bl[128 * 32];

    const int tid  = threadIdx.x;
    const int wave = tid >> 6, lane = tid & 63;
    const int quad = lane >> 4, l16 = lane & 15;
    const int wM = wave >> 1, wN = wave & 1;
    const int bM = blockIdx.x, bN = blockIdx.y;

    f4v acc[4][4];
#pragma unroll
    for (int i = 0; i < 4; i++)
#pragma unroll
        for (int j = 0; j < 4; j++) { f4v z = {0.f, 0.f, 0.f, 0.f}; acc[i][j] = z; }

    const uint16_t* Ag = A  + (size_t)bM * 128 * K;
    const uint16_t* Bg = Bm + (size_t)bN * 128 * K;

    const int e0 = tid * 8;
    const int r0 = e0 >> 5, c0 = e0 & 31;

    for (int kc = 0; kc < K; kc += 32) {
        __syncthreads();
        cp16(Ag + (size_t)r0 * K + kc + c0,        &Al[e0]);
        cp16(Ag + (size_t)(r0 + 64) * K + kc + c0, &Al[e0 + 2048]);
        cp16(Bg + (size_t)r0 * K + kc + c0,        &Bl[e0]);
        cp16(Bg + (size_t)(r0 + 64) * K + kc + c0, &Bl[e0 + 2048]);
        __syncthreads();

        s8v af[4], bf[4];
#pragma unroll
        for (int t = 0; t < 4; t++) {
            af[t] = *reinterpret_cast<const s8v*>(&Al[(wM * 64 + t * 16 + l16) * 32 + quad * 8]);
            bf[t] = *reinterpret_cast<const s8v*>(&Bl[(wN * 64 + t * 16 + l16) * 32 + quad * 8]);
        }
#pragma unroll
        for (int tm = 0; tm < 4; tm++)
#pragma unroll
            for (int tn = 0; tn < 4; tn++)
                acc[tm][tn] = __builtin_amdgcn_mfma_f32_16x16x32_bf16(af[tm], bf[tn], acc[tm][tn], 0, 0, 0);
    }

#pragma unroll
    for (int tm = 0; tm < 4; tm++) {
#pragma unroll
        for (int tn = 0; tn < 4; tn++) {
            const int col = bN * 128 + wN * 64 + tn * 16 + l16;
#pragma unroll
            for (int reg = 0; reg < 4; reg++) {
                const int row = bM * 128 + wM * 64 + tm * 16 + quad * 4 + reg;
                float val = acc[tm][tn][reg];
                if (EPI == 0) {
                    const int three = col / 768;
                    const int rem   = col - three * 768;
                    const int h = rem >> 6, d = rem & 63;
                    const int b = row >> 10, n = row & 1023;
                    if (three == 0)
                        qb[((size_t)((b * 12 + h) * 1024 + n)) * 64 + d] = f2bf(val);
                    else if (three == 1)
                        kb[((size_t)((b * 12 + h) * 1024 + n)) * 64 + d] = f2bf(val);
                    else  // V transposed: [b,h,d,n]
                        vb[((size_t)((b * 12 + h) * 64 + d)) * 1024 + n] = f2bf(val);
                } else {
                    Cout[(size_t)row * 768 + col] = val + bias[col];
                }
            }
        }
    }
}

// ---------------------------------------------------------------------------
// Fused quad2 attention (R4 body + internal Kl/Vl XOR chunk swizzle).
// Grid: x=8 (128 q-rows/block), y=96 (b*12+h). 2 waves; wave owns 64 q-rows
// as 4 subtiles. Per m-tile: swizzled cp16 stage of K[m][d], V^T[d][m]
// (logical chunk c of row r lives at physical chunk c^(r&7)); hoist K/V
// frags (reads XOR back -> structural 8-cyc, no 16-way conflict);
// S^T = K@Q^T -> t=(s/8+5)^2 -> packed b64 P writes -> PV + ones-MFMA
// rowsum. Final O = U/rowsum.
// ---------------------------------------------------------------------------
__global__ __launch_bounds__(128, 2) void attn_quad(
    const uint16_t* __restrict__ Q, const uint16_t* __restrict__ K,
    const uint16_t* __restrict__ VT, uint16_t* __restrict__ O)
{
    const int qt = blockIdx.x;      // 0..7
    const int bh = blockIdx.y;      // 0..95
    const int b = bh / 12, h = bh - (bh / 12) * 12;
    const uint16_t* Qp = Q  + (size_t)bh * 65536;
    const uint16_t* Kp = K  + (size_t)bh * 65536;
    const uint16_t* Vp = VT + (size_t)bh * 65536;   // [d=64][n=1024]

    const int tid  = threadIdx.x;
    const int wave = tid >> 6, lane = tid & 63;
    const int quad = lane >> 4, l16 = lane & 15;

    __shared__ uint16_t Kl[64 * 64];     // [key][d], chunk-swizzled
    __shared__ uint16_t Vl[64 * 64];     // [d][m],  chunk-swizzled
    __shared__ uint16_t Pl[2][16][80];   // per-wave [qrow][m], stride 80 (R4)

    // Q fragments (one-time, direct global)
    s8v qf[4][2];
#pragma unroll
    for (int s = 0; s < 4; s++) {
        const uint16_t* qp = Qp + (size_t)(qt * 128 + wave * 64 + s * 16 + l16) * 64 + quad * 8;
        qf[s][0] = *reinterpret_cast<const s8v*>(qp);
        qf[s][1] = *reinterpret_cast<const s8v*>(qp + 32);
    }

    s8v ones;
#pragma unroll
    for (int i = 0; i < 8; i++) ones[i] = (short)0x3F80;   // bf16 1.0

    f4v U[4][4], U5[4];
#pragma unroll
    for (int s = 0; s < 4; s++) {
        f4v z = {0.f, 0.f, 0.f, 0.f};
        U5[s] = z;
#pragma unroll
        for (int c = 0; c < 4; c++) U[s][c] = z;
    }

    for (int mt = 0; mt < 16; mt++) {
        __syncthreads();
        // swizzled staging: physical chunk pc of row holds logical pc^(row&7)
#pragma unroll
        for (int r = 0; r < 4; r++) {
            const int e   = (tid + r * 128) * 8;
            const int row = e >> 6;                       // key for K, d for V
            const int cl  = ((e >> 3) & 7) ^ (row & 7);   // logical chunk fetched
            cp16(Kp + (size_t)mt * 4096 + (size_t)row * 64 + cl * 8, &Kl[e]);
            cp16(Vp + (size_t)row * 1024 + mt * 64 + cl * 8, &Vl[e]);
        }
        __syncthreads();

        // hoist K/V fragments (reused by all 4 subtiles); XOR-swizzled reads
        s8v kf[4][2], vf[4][2];
#pragma unroll
        for (int c = 0; c < 4; c++) {
            const int rr = c * 16 + l16;
#pragma unroll
            for (int kk = 0; kk < 2; kk++) {
                const int pc = (kk * 4 + quad) ^ (rr & 7);
                kf[c][kk] = *reinterpret_cast<const s8v*>(&Kl[rr * 64 + (pc << 3)]);
                vf[c][kk] = *reinterpret_cast<const s8v*>(&Vl[rr * 64 + (pc << 3)]);
            }
        }

#pragma unroll
        for (int s = 0; s < 4; s++) {
            // S^T = K @ Q^T : C col=l16=qrow, row=quad*4+reg = m (in cm tile)
            f4v st[4];
#pragma unroll
            for (int cm = 0; cm < 4; cm++) {
                f4v z = {0.f, 0.f, 0.f, 0.f};
                z = __builtin_amdgcn_mfma_f32_16x16x32_bf16(kf[cm][0], qf[s][0], z, 0, 0, 0);
                z = __builtin_amdgcn_mfma_f32_16x16x32_bf16(kf[cm][1], qf[s][1], z, 0, 0, 0);
                st[cm] = z;
            }
            // t = (s*0.125+5)^2 -> packed b64 write: Pl[l16][cm*16+quad*4 ..+3]
#pragma unroll
            for (int cm = 0; cm < 4; cm++) {
                float t0 = st[cm][0] * 0.125f + 5.0f; t0 *= t0;
                float t1 = st[cm][1] * 0.125f + 5.0f; t1 *= t1;
                float t2 = st[cm][2] * 0.125f + 5.0f; t2 *= t2;
                float t3 = st[cm][3] * 0.125f + 5.0f; t3 *= t3;
                uint2 pk; pk.x = pack2bf(t0, t1); pk.y = pack2bf(t2, t3);
                *reinterpret_cast<uint2*>(&Pl[wave][l16][cm * 16 + quad * 4]) = pk;
            }
            // U += P @ V ; rowsum via ones-MFMA (same-wave DS in-order)
#pragma unroll
            for (int kc = 0; kc < 2; kc++) {
                s8v pf = *reinterpret_cast<const s8v*>(&Pl[wave][l16][kc * 32 + quad * 8]);
                U5[s] = __builtin_amdgcn_mfma_f32_16x16x32_bf16(pf, ones, U5[s], 0, 0, 0);
#pragma unroll
                for (int cd = 0; cd < 4; cd++)
                    U[s][cd] = __builtin_amdgcn_mfma_f32_16x16x32_bf16(pf, vf[cd][kc], U[s][cd], 0, 0, 0);
            }
        }
    }

    // epilogue: O[b, n, h*64+d] = U / rowsum (bf16 intermediate for proj GEMM)
#pragma unroll
    for (int s = 0; s < 4; s++) {
        float inv[4];
#pragma unroll
        for (int reg = 0; reg < 4; reg++) inv[reg] = 1.0f / U5[s][reg];
#pragma unroll
        for (int cd = 0; cd < 4; cd++) {
#pragma unroll
            for (int reg = 0; reg < 4; reg++) {
                const int n = qt * 128 + wave * 64 + s * 16 + quad * 4 + reg;
                const int d = cd * 16 + l16;
                O[((size_t)(b * 1024 + n)) * 768 + h * 64 + d] = f2bf(U[s][cd][reg] * inv[reg]);
            }
        }
    }
}

// ---------------------------------------------------------------------------
extern "C" void kernel_launch(void* const* d_in, const int* in_sizes, int n_in,
                              void* d_out, int out_size, void* d_ws, size_t ws_size,
                              hipStream_t stream)
{
    const float* x      = (const float*)d_in[0];   // [8,1024,768]
    const float* qkv_w  = (const float*)d_in[1];   // [2304,768]
    const float* proj_w = (const float*)d_in[2];   // [768,768]
    const float* proj_b = (const float*)d_in[3];   // [768]
    float* out = (float*)d_out;                    // [8,1024,768] fp32

    const size_t NEL = (size_t)8 * 1024 * 768;     // 6291456
    uint16_t* xb  = (uint16_t*)d_ws;               // bf16 x
    uint16_t* qwb = xb  + NEL;                     // bf16 qkv_w (1769472)
    uint16_t* pwb = qwb + 1769472;                 // bf16 proj_w (589824)
    uint16_t* qb  = pwb + 589824;                  // bf16 [B,H,N,64]
    uint16_t* kb  = qb  + NEL;                     // bf16 [B,H,N,64]
    uint16_t* vb  = kb  + NEL;                     // bf16 [B,H,64,N] (transposed)
    uint16_t* ao  = vb  + NEL;                     // bf16 attn out [8192,768]

    cvt_all<<<4224, 256, 0, stream>>>(x, qkv_w, proj_w, xb);

    // QKV: [8192,768] @ [2304,768]^T -> scatter bf16 q/k/v (v transposed)
    gemm_bt<0><<<dim3(64, 18), 256, 0, stream>>>(xb, qwb, qb, kb, vb, nullptr, nullptr, 768);
    // fused quad2 attention -> ao [8192,768] bf16
    attn_quad<<<dim3(8, 96), 128, 0, stream>>>(qb, kb, vb, ao);
    // proj: [8192,768] @ [768,768]^T + bias -> fp32 out
    gemm_bt<1><<<dim3(64, 6), 256, 0, stream>>>(ao, pwb, nullptr, nullptr, nullptr, proj_b, out, 768);
}

// Round 10
// 198.941 us; speedup vs baseline: 1.6984x; 1.0490x over previous
//
#include <hip/hip_runtime.h>
#include <hip/hip_bf16.h>
#include <stdint.h>

// ---------------------------------------------------------------------------
// Attention_47330539602252 on MI355X (gfx950). fp32 I/O, bf16 MFMA compute.
// B=8 N=1024 C=768 H=12 hd=64; quad2: t=(s*0.125+5)^2, row-normalized.
// R10 = R8 (PASS 208.7us) + EXACTLY ONE change: the gemm_bt<0> V epilogue
// (three==2) packs each lane's 4 C-layout regs (4 consecutive tokens at
// fixed vdim) into one ushort4 store. Staging/BK/swizzle byte-identical to
// R8 (BK=32, unswizzled gemm; swizzled attn). Bisect: if this FAILS,
// packed-V is the R9 culprit; if it PASSES, BK=64-gemm-swizzle is.
// MFMA layouts (HW-verified):
//   A-frag: A[m=lane&15][k=quad*8+j]   B-frag: B[n=lane&15][k=quad*8+j]
//   C/D:    col(n)=lane&15, row(m)=quad*4+reg
// ---------------------------------------------------------------------------

typedef short  s8v  __attribute__((ext_vector_type(8)));  // 8 bf16 raw bits
typedef float  f4v  __attribute__((ext_vector_type(4)));

__device__ inline uint16_t f2bf(float f) {
    union { float f; uint32_t u; } c; c.f = f;
    uint32_t u = c.u;
    u += 0x7fffu + ((u >> 16) & 1u);   // RNE
    return (uint16_t)(u >> 16);
}
__device__ inline uint32_t pack2bf(float a, float b) {
    union { __hip_bfloat162 v; uint32_t u; } c;
    c.v = __float22bfloat162_rn(float2{a, b});   // x=a -> low 16 bits
    return c.u;
}

// async global->LDS, 16B per lane (LDS dest = wave-uniform base + lane*16)
__device__ inline void cp16(const uint16_t* g, uint16_t* l) {
    __builtin_amdgcn_global_load_lds(
        (const __attribute__((address_space(1))) void*)g,
        (__attribute__((address_space(3))) void*)l, 16, 0, 0);
}

// ---------------------------------------------------------------------------
// fp32 -> bf16 for all three inputs in one launch (dests contiguous in ws).
// ---------------------------------------------------------------------------
__global__ __launch_bounds__(256) void cvt_all(
    const float* __restrict__ x, const float* __restrict__ qw,
    const float* __restrict__ pw, uint16_t* __restrict__ dst)
{
    // totals in 8-elem groups: x 786432 | qkv_w 221184 | proj_w 73728
    int i = blockIdx.x * 256 + threadIdx.x;
    if (i >= 1081344) return;
    const float* s;
    if (i < 786432)       s = x  + (size_t)i * 8;
    else if (i < 1007616) s = qw + ((size_t)i - 786432) * 8;
    else                  s = pw + ((size_t)i - 1007616) * 8;
    const float4* sp = reinterpret_cast<const float4*>(s);
    float4 a = sp[0], b = sp[1];
    s8v o;
    o[0] = (short)f2bf(a.x); o[1] = (short)f2bf(a.y);
    o[2] = (short)f2bf(a.z); o[3] = (short)f2bf(a.w);
    o[4] = (short)f2bf(b.x); o[5] = (short)f2bf(b.y);
    o[6] = (short)f2bf(b.z); o[7] = (short)f2bf(b.w);
    *reinterpret_cast<s8v*>(dst + (size_t)i * 8) = o;
}

// ---------------------------------------------------------------------------
// GEMM-BT (R8 body; only the V store packed): C[M,N] = A[M,K] @ Bm[N,K]^T,
// bf16 in, K%32==0. 128x128 tile, 4 waves (2x2), 4x4 mfma tiles/wave,
// BK=32 cp16 staging (unswizzled, R8-identical).
// EPI==0: q/k scalar scatter; V packed ushort4 into [b,h,d,n].
// EPI==1: +bias, fp32 Cout[M,768].
// ---------------------------------------------------------------------------
template <int EPI>
__global__ __launch_bounds__(256) void gemm_bt(
    const uint16_t* __restrict__ A, const uint16_t* __restrict__ Bm,
    uint16_t* __restrict__ qb, uint16_t* __restrict__ kb, uint16_t* __restrict__ vb,
    const float* __restrict__ bias, float* __restrict__ Cout, int K)
{
    __shared__ uint16_t Al[128 * 32];
    __shared__ uint16_t Bl[128 * 32];

    const int tid  = threadIdx.x;
    const int wave = tid >> 6, lane = tid & 63;
    const int quad = lane >> 4, l16 = lane & 15;
    const int wM = wave >> 1, wN = wave & 1;
    const int bM = blockIdx.x, bN = blockIdx.y;

    f4v acc[4][4];
#pragma unroll
    for (int i = 0; i < 4; i++)
#pragma unroll
        for (int j = 0; j < 4; j++) { f4v z = {0.f, 0.f, 0.f, 0.f}; acc[i][j] = z; }

    const uint16_t* Ag = A  + (size_t)bM * 128 * K;
    const uint16_t* Bg = Bm + (size_t)bN * 128 * K;

    const int e0 = tid * 8;
    const int r0 = e0 >> 5, c0 = e0 & 31;

    for (int kc = 0; kc < K; kc += 32) {
        __syncthreads();
        cp16(Ag + (size_t)r0 * K + kc + c0,        &Al[e0]);
        cp16(Ag + (size_t)(r0 + 64) * K + kc + c0, &Al[e0 + 2048]);
        cp16(Bg + (size_t)r0 * K + kc + c0,        &Bl[e0]);
        cp16(Bg + (size_t)(r0 + 64) * K + kc + c0, &Bl[e0 + 2048]);
        __syncthreads();

        s8v af[4], bf[4];
#pragma unroll
        for (int t = 0; t < 4; t++) {
            af[t] = *reinterpret_cast<const s8v*>(&Al[(wM * 64 + t * 16 + l16) * 32 + quad * 8]);
            bf[t] = *reinterpret_cast<const s8v*>(&Bl[(wN * 64 + t * 16 + l16) * 32 + quad * 8]);
        }
#pragma unroll
        for (int tm = 0; tm < 4; tm++)
#pragma unroll
            for (int tn = 0; tn < 4; tn++)
                acc[tm][tn] = __builtin_amdgcn_mfma_f32_16x16x32_bf16(af[tm], bf[tn], acc[tm][tn], 0, 0, 0);
    }

#pragma unroll
    for (int tm = 0; tm < 4; tm++) {
#pragma unroll
        for (int tn = 0; tn < 4; tn++) {
            const int col = bN * 128 + wN * 64 + tn * 16 + l16;
            if (EPI == 0) {
                const int three = col / 768;          // block-uniform (128 | 768)
                const int rem   = col - three * 768;
                const int h = rem >> 6, d = rem & 63;
                const int n0 = bM * 128 + wM * 64 + tm * 16 + quad * 4;
                const int b = n0 >> 10, n = n0 & 1023;   // n0%4==0: no b crossing
                if (three == 2) {
                    // V: 4 regs = 4 consecutive tokens at fixed vdim -> ushort4
                    ushort4 pk;
                    pk.x = f2bf(acc[tm][tn][0]);
                    pk.y = f2bf(acc[tm][tn][1]);
                    pk.z = f2bf(acc[tm][tn][2]);
                    pk.w = f2bf(acc[tm][tn][3]);
                    *reinterpret_cast<ushort4*>(
                        &vb[((size_t)((b * 12 + h) * 64 + d)) * 1024 + n]) = pk;
                } else {
                    uint16_t* dst = (three == 0) ? qb : kb;
#pragma unroll
                    for (int reg = 0; reg < 4; reg++)
                        dst[((size_t)((b * 12 + h) * 1024 + n + reg)) * 64 + d] =
                            f2bf(acc[tm][tn][reg]);
                }
            } else {
#pragma unroll
                for (int reg = 0; reg < 4; reg++) {
                    const int row = bM * 128 + wM * 64 + tm * 16 + quad * 4 + reg;
                    Cout[(size_t)row * 768 + col] = acc[tm][tn][reg] + bias[col];
                }
            }
        }
    }
}

// ---------------------------------------------------------------------------
// Fused quad2 attention (byte-identical to R8 PASS).
// Grid: x=8 (128 q-rows/block), y=96 (b*12+h). 2 waves; wave owns 64 q-rows
// as 4 subtiles. Per m-tile: swizzled cp16 stage of K[m][d], V^T[d][m];
// hoist K/V frags (XOR-swizzled reads); S^T = K@Q^T -> t=(s/8+5)^2 ->
// packed b64 P writes -> PV + ones-MFMA rowsum. Final O = U/rowsum.
// ---------------------------------------------------------------------------
__global__ __launch_bounds__(128, 2) void attn_quad(
    const uint16_t* __restrict__ Q, const uint16_t* __restrict__ K,
    const uint16_t* __restrict__ VT, uint16_t* __restrict__ O)
{
    const int qt = blockIdx.x;      // 0..7
    const int bh = blockIdx.y;      // 0..95
    const int b = bh / 12, h = bh - (bh / 12) * 12;
    const uint16_t* Qp = Q  + (size_t)bh * 65536;
    const uint16_t* Kp = K  + (size_t)bh * 65536;
    const uint16_t* Vp = VT + (size_t)bh * 65536;   // [d=64][n=1024]

    const int tid  = threadIdx.x;
    const int wave = tid >> 6, lane = tid & 63;
    const int quad = lane >> 4, l16 = lane & 15;

    __shared__ uint16_t Kl[64 * 64];     // [key][d], chunk-swizzled
    __shared__ uint16_t Vl[64 * 64];     // [d][m],  chunk-swizzled
    __shared__ uint16_t Pl[2][16][80];   // per-wave [qrow][m], stride 80

    // Q fragments (one-time, direct global)
    s8v qf[4][2];
#pragma unroll
    for (int s = 0; s < 4; s++) {
        const uint16_t* qp = Qp + (size_t)(qt * 128 + wave * 64 + s * 16 + l16) * 64 + quad * 8;
        qf[s][0] = *reinterpret_cast<const s8v*>(qp);
        qf[s][1] = *reinterpret_cast<const s8v*>(qp + 32);
    }

    s8v ones;
#pragma unroll
    for (int i = 0; i < 8; i++) ones[i] = (short)0x3F80;   // bf16 1.0

    f4v U[4][4], U5[4];
#pragma unroll
    for (int s = 0; s < 4; s++) {
        f4v z = {0.f, 0.f, 0.f, 0.f};
        U5[s] = z;
#pragma unroll
        for (int c = 0; c < 4; c++) U[s][c] = z;
    }

    for (int mt = 0; mt < 16; mt++) {
        __syncthreads();
        // swizzled staging: physical chunk pc of row holds logical pc^(row&7)
#pragma unroll
        for (int r = 0; r < 4; r++) {
            const int e   = (tid + r * 128) * 8;
            const int row = e >> 6;                       // key for K, d for V
            const int cl  = ((e >> 3) & 7) ^ (row & 7);   // logical chunk fetched
            cp16(Kp + (size_t)mt * 4096 + (size_t)row * 64 + cl * 8, &Kl[e]);
            cp16(Vp + (size_t)row * 1024 + mt * 64 + cl * 8, &Vl[e]);
        }
        __syncthreads();

        // hoist K/V fragments (reused by all 4 subtiles); XOR-swizzled reads
        s8v kf[4][2], vf[4][2];
#pragma unroll
        for (int c = 0; c < 4; c++) {
            const int rr = c * 16 + l16;
#pragma unroll
            for (int kk = 0; kk < 2; kk++) {
                const int pc = (kk * 4 + quad) ^ (rr & 7);
                kf[c][kk] = *reinterpret_cast<const s8v*>(&Kl[rr * 64 + (pc << 3)]);
                vf[c][kk] = *reinterpret_cast<const s8v*>(&Vl[rr * 64 + (pc << 3)]);
            }
        }

#pragma unroll
        for (int s = 0; s < 4; s++) {
            // S^T = K @ Q^T : C col=l16=qrow, row=quad*4+reg = m (in cm tile)
            f4v st[4];
#pragma unroll
            for (int cm = 0; cm < 4; cm++) {
                f4v z = {0.f, 0.f, 0.f, 0.f};
                z = __builtin_amdgcn_mfma_f32_16x16x32_bf16(kf[cm][0], qf[s][0], z, 0, 0, 0);
                z = __builtin_amdgcn_mfma_f32_16x16x32_bf16(kf[cm][1], qf[s][1], z, 0, 0, 0);
                st[cm] = z;
            }
            // t = (s*0.125+5)^2 -> packed b64 write: Pl[l16][cm*16+quad*4 ..+3]
#pragma unroll
            for (int cm = 0; cm < 4; cm++) {
                float t0 = st[cm][0] * 0.125f + 5.0f; t0 *= t0;
                float t1 = st[cm][1] * 0.125f + 5.0f; t1 *= t1;
                float t2 = st[cm][2] * 0.125f + 5.0f; t2 *= t2;
                float t3 = st[cm][3] * 0.125f + 5.0f; t3 *= t3;
                uint2 pk; pk.x = pack2bf(t0, t1); pk.y = pack2bf(t2, t3);
                *reinterpret_cast<uint2*>(&Pl[wave][l16][cm * 16 + quad * 4]) = pk;
            }
            // U += P @ V ; rowsum via ones-MFMA (same-wave DS in-order)
#pragma unroll
            for (int kc = 0; kc < 2; kc++) {
                s8v pf = *reinterpret_cast<const s8v*>(&Pl[wave][l16][kc * 32 + quad * 8]);
                U5[s] = __builtin_amdgcn_mfma_f32_16x16x32_bf16(pf, ones, U5[s], 0, 0, 0);
#pragma unroll
                for (int cd = 0; cd < 4; cd++)
                    U[s][cd] = __builtin_amdgcn_mfma_f32_16x16x32_bf16(pf, vf[cd][kc], U[s][cd], 0, 0, 0);
            }
        }
    }

    // epilogue: O[b, n, h*64+d] = U / rowsum (bf16 intermediate for proj GEMM)
#pragma unroll
    for (int s = 0; s < 4; s++) {
        float inv[4];
#pragma unroll
        for (int reg = 0; reg < 4; reg++) inv[reg] = 1.0f / U5[s][reg];
#pragma unroll
        for (int cd = 0; cd < 4; cd++) {
#pragma unroll
            for (int reg = 0; reg < 4; reg++) {
                const int n = qt * 128 + wave * 64 + s * 16 + quad * 4 + reg;
                const int d = cd * 16 + l16;
                O[((size_t)(b * 1024 + n)) * 768 + h * 64 + d] = f2bf(U[s][cd][reg] * inv[reg]);
            }
        }
    }
}

// ---------------------------------------------------------------------------
extern "C" void kernel_launch(void* const* d_in, const int* in_sizes, int n_in,
                              void* d_out, int out_size, void* d_ws, size_t ws_size,
                              hipStream_t stream)
{
    const float* x      = (const float*)d_in[0];   // [8,1024,768]
    const float* qkv_w  = (const float*)d_in[1];   // [2304,768]
    const float* proj_w = (const float*)d_in[2];   // [768,768]
    const float* proj_b = (const float*)d_in[3];   // [768]
    float* out = (float*)d_out;                    // [8,1024,768] fp32

    const size_t NEL = (size_t)8 * 1024 * 768;     // 6291456
    uint16_t* xb  = (uint16_t*)d_ws;               // bf16 x
    uint16_t* qwb = xb  + NEL;                     // bf16 qkv_w (1769472)
    uint16_t* pwb = qwb + 1769472;                 // bf16 proj_w (589824)
    uint16_t* qb  = pwb + 589824;                  // bf16 [B,H,N,64]
    uint16_t* kb  = qb  + NEL;                     // bf16 [B,H,N,64]
    uint16_t* vb  = kb  + NEL;                     // bf16 [B,H,64,N] (transposed)
    uint16_t* ao  = vb  + NEL;                     // bf16 attn out [8192,768]

    cvt_all<<<4224, 256, 0, stream>>>(x, qkv_w, proj_w, xb);

    // QKV: [8192,768] @ [2304,768]^T -> q/k scalar scatter + V packed ushort4
    gemm_bt<0><<<dim3(64, 18), 256, 0, stream>>>(xb, qwb, qb, kb, vb, nullptr, nullptr, 768);
    // fused quad2 attention -> ao [8192,768] bf16
    attn_quad<<<dim3(8, 96), 128, 0, stream>>>(qb, kb, vb, ao);
    // proj: [8192,768] @ [768,768]^T + bias -> fp32 out
    gemm_bt<1><<<dim3(64, 6), 256, 0, stream>>>(ao, pwb, nullptr, nullptr, nullptr, proj_b, out, 768);
}